// Round 8
// baseline (371.119 us; speedup 1.0000x reference)
//
#include <hip/hip_runtime.h>
#include <hip/hip_bf16.h>

// LightGCN forward: x0 = concat(user_emb, item_emb); 3x { x = A*x }; out = (x0+x1+x2+x3)/4.
// Sorted COO -> CSR row_ptr (binary search). Edges pre-expanded into PADDED
// array pe[]: row r's segment starts at row_ptr[r] + 4*r (capacity deg+4),
// entry = {byte offset col*128, val fp32}, zero-padded to multiple of 4.
// SpMM: one 8-LANE GROUP per row; lane holds 8 dims (dwordx4 = whole 128B
// bf16 row per gather). Hot path: unconditionally load 16 pe entries +
// issue 16 masked gathers (2KB/wave in flight, one exposed latency chain);
// rows with deg>16 (~3%) take a 4-wide tail loop. Layer 3 fused with mean.

#define EMB 64

typedef unsigned short u16;
typedef unsigned int   u32;
typedef unsigned long long u64;

__device__ __forceinline__ u16 f2bf(float f) {      // round-to-nearest-even
    u32 u = __float_as_uint(f);
    return (u16)((u + 0x7FFFu + ((u >> 16) & 1u)) >> 16);
}
__device__ __forceinline__ float bflo(u32 p) { return __uint_as_float(p << 16); }
__device__ __forceinline__ float bfhi(u32 p) { return __uint_as_float(p & 0xFFFF0000u); }
__device__ __forceinline__ u32 pack2(float hi, float lo) {
    return ((u32)f2bf(hi) << 16) | (u32)f2bf(lo);
}

__global__ void init_x_kernel(const float4* __restrict__ user,
                              const float4* __restrict__ item,
                              ushort4* __restrict__ x,
                              int n_user_vec, int n_total_vec) {
    int i = blockIdx.x * blockDim.x + threadIdx.x;
    if (i >= n_total_vec) return;
    float4 v = (i < n_user_vec) ? user[i] : item[i - n_user_vec];
    ushort4 o;
    o.x = f2bf(v.x); o.y = f2bf(v.y); o.z = f2bf(v.z); o.w = f2bf(v.w);
    x[i] = o;
}

// row_ptr[r] = lower_bound(rows, r); rows sorted.
__global__ void build_row_ptr_kernel(const int* __restrict__ rows, int nnz,
                                     int n_rows, int* __restrict__ row_ptr) {
    int r = blockIdx.x * blockDim.x + threadIdx.x;
    if (r > n_rows) return;
    int lo = 0, hi = nnz;
    while (lo < hi) {
        int mid = (lo + hi) >> 1;
        if (rows[mid] < r) lo = mid + 1; else hi = mid;
    }
    row_ptr[r] = lo;
}

// pe[e + 4*rows[e]] = {cols[e]*128, vals[e]}; last edge of each row zero-fills
// the <=3 pad slots up to the row's ceil4(deg) boundary.
__global__ void expand_kernel(const int* __restrict__ rows,
                              const int* __restrict__ cols,
                              const float* __restrict__ vals,
                              const int* __restrict__ row_ptr,
                              int nnz, int2* __restrict__ pe) {
    int e = blockIdx.x * blockDim.x + threadIdx.x;
    if (e >= nnz) return;
    int r = rows[e];
    int dst = e + 4 * r;
    int2 ent;
    ent.x = cols[e] << 7;                    // byte offset into bf16 x table
    ent.y = __float_as_int(vals[e]);
    pe[dst] = ent;
    bool last = (e == nnz - 1) || (rows[e + 1] != r);
    if (last) {
        int s   = row_ptr[r];
        int deg = e + 1 - s;
        int cnt = (deg + 3) & ~3;
        int lim = s + 4 * r + cnt;           // segment start + padded count
        int2 z; z.x = 0; z.y = 0;
        for (int j = dst + 1; j < lim; ++j) pe[j] = z;
    }
}

// Core row accumulate for one 8-lane group. lane sub holds dims 8sub..8sub+7.
// Unconditional 16-entry block (masked); rare tail for cnt > 16.
__device__ __forceinline__ void spmm_row16(const int2* __restrict__ pe,
                                           const char* __restrict__ xb,
                                           int ps, int cnt, u32 lane_byte,
                                           float* a /*[8]*/) {
#pragma unroll
    for (int k = 0; k < 8; ++k) a[k] = 0.0f;

    const u64* pq = (const u64*)(pe + ps);
    u32   offs[16];
    float vv[16];
#pragma unroll
    for (int k = 0; k < 16; ++k) {
        u64 q = __builtin_nontemporal_load(&pq[k]);   // uniform across group
        bool ok = k < cnt;
        offs[k] = ok ? (u32)q : 0u;                   // masked -> x[0] (L1-hot)
        vv[k]   = ok ? __uint_as_float((u32)(q >> 32)) : 0.0f;
    }
    uint4 xp[16];
#pragma unroll
    for (int k = 0; k < 16; ++k)
        xp[k] = *(const uint4*)(xb + (offs[k] + lane_byte));
#pragma unroll
    for (int k = 0; k < 16; ++k) {
        float v = vv[k];
        a[0] = fmaf(v, bflo(xp[k].x), a[0]);
        a[1] = fmaf(v, bfhi(xp[k].x), a[1]);
        a[2] = fmaf(v, bflo(xp[k].y), a[2]);
        a[3] = fmaf(v, bfhi(xp[k].y), a[3]);
        a[4] = fmaf(v, bflo(xp[k].z), a[4]);
        a[5] = fmaf(v, bfhi(xp[k].z), a[5]);
        a[6] = fmaf(v, bflo(xp[k].w), a[6]);
        a[7] = fmaf(v, bfhi(xp[k].w), a[7]);
    }

    // tail: deg > 16 (~3% of rows), 4-wide
    for (int j = 16; j < cnt; j += 4) {
        int2 ent[4];
#pragma unroll
        for (int k = 0; k < 4; ++k) ent[k] = pe[ps + j + k];
        uint4 tp[4];
#pragma unroll
        for (int k = 0; k < 4; ++k)
            tp[k] = *(const uint4*)(xb + ((u32)ent[k].x + lane_byte));
#pragma unroll
        for (int k = 0; k < 4; ++k) {
            float v = __int_as_float(ent[k].y);
            a[0] = fmaf(v, bflo(tp[k].x), a[0]);
            a[1] = fmaf(v, bfhi(tp[k].x), a[1]);
            a[2] = fmaf(v, bflo(tp[k].y), a[2]);
            a[3] = fmaf(v, bfhi(tp[k].y), a[3]);
            a[4] = fmaf(v, bflo(tp[k].z), a[4]);
            a[5] = fmaf(v, bfhi(tp[k].z), a[5]);
            a[6] = fmaf(v, bflo(tp[k].w), a[6]);
            a[7] = fmaf(v, bfhi(tp[k].w), a[7]);
        }
    }
}

__global__ void spmm_kernel(const int* __restrict__ row_ptr,
                            const int2* __restrict__ pe,
                            const u32* __restrict__ x,    // bf16x2 table [n*32]
                            uint4* __restrict__ y,        // bf16 rows as uint4 [n*8]
                            int n_rows) {
    int tid = blockIdx.x * blockDim.x + threadIdx.x;
    int row = tid >> 3;
    int sub = threadIdx.x & 7;
    if (row >= n_rows) return;

    int s   = row_ptr[row];
    int deg = row_ptr[row + 1] - s;
    int cnt = (deg + 3) & ~3;
    int ps  = s + 4 * row;

    float a[8];
    spmm_row16(pe, (const char*)x, ps, cnt, (u32)sub * 16u, a);

    uint4 w;
    w.x = pack2(a[1], a[0]);
    w.y = pack2(a[3], a[2]);
    w.z = pack2(a[5], a[4]);
    w.w = pack2(a[7], a[6]);
    y[(size_t)row * 8 + sub] = w;
}

// Layer 3 fused with epilogue: out = (x0 + y1 + y2 + A*y2) * 0.25 (fp32 out).
__global__ void spmm_final_kernel(const int* __restrict__ row_ptr,
                                  const int2* __restrict__ pe,
                                  const uint4* __restrict__ x0,   // bf16 rows [n*8]
                                  const uint4* __restrict__ y1,
                                  const uint4* __restrict__ y2,   // also gather src
                                  float4* __restrict__ out,       // [n*16]
                                  int n_rows) {
    int tid = blockIdx.x * blockDim.x + threadIdx.x;
    int row = tid >> 3;
    int sub = threadIdx.x & 7;
    if (row >= n_rows) return;

    int s   = row_ptr[row];
    int deg = row_ptr[row + 1] - s;
    int cnt = (deg + 3) & ~3;
    int ps  = s + 4 * row;

    float a[8];
    spmm_row16(pe, (const char*)y2, ps, cnt, (u32)sub * 16u, a);

    size_t i8 = (size_t)row * 8 + sub;
    uint4 b0 = x0[i8], b1 = y1[i8], b2 = y2[i8];
    float4 r0, r1;
    r0.x = (bflo(b0.x) + bflo(b1.x) + bflo(b2.x) + a[0]) * 0.25f;
    r0.y = (bfhi(b0.x) + bfhi(b1.x) + bfhi(b2.x) + a[1]) * 0.25f;
    r0.z = (bflo(b0.y) + bflo(b1.y) + bflo(b2.y) + a[2]) * 0.25f;
    r0.w = (bfhi(b0.y) + bfhi(b1.y) + bfhi(b2.y) + a[3]) * 0.25f;
    r1.x = (bflo(b0.z) + bflo(b1.z) + bflo(b2.z) + a[4]) * 0.25f;
    r1.y = (bfhi(b0.z) + bfhi(b1.z) + bfhi(b2.z) + a[5]) * 0.25f;
    r1.z = (bflo(b0.w) + bflo(b1.w) + bflo(b2.w) + a[6]) * 0.25f;
    r1.w = (bfhi(b0.w) + bfhi(b1.w) + bfhi(b2.w) + a[7]) * 0.25f;
    size_t o4 = (size_t)row * 16 + (size_t)sub * 2;
    out[o4]     = r0;
    out[o4 + 1] = r1;
}

extern "C" void kernel_launch(void* const* d_in, const int* in_sizes, int n_in,
                              void* d_out, int out_size, void* d_ws, size_t ws_size,
                              hipStream_t stream) {
    const float* user_emb = (const float*)d_in[0];
    const float* item_emb = (const float*)d_in[1];
    const int*   adj_rows = (const int*)d_in[2];
    const int*   adj_cols = (const int*)d_in[3];
    const float* adj_vals = (const float*)d_in[4];

    const int n_users = in_sizes[0] / EMB;
    const int n_items = in_sizes[1] / EMB;
    const int nnz     = in_sizes[2];
    const int n       = n_users + n_items;

    char* ws = (char*)d_ws;
    size_t xbytes  = (size_t)n * EMB * sizeof(u16);                // 38.4 MB
    // +16 entries slack: spmm_row16 reads up to 15 entries past the last
    // segment (masked, never dereferenced as gather addresses).
    size_t pebytes = ((size_t)nnz + 4 * (size_t)n + 16) * sizeof(int2);
    u32*  x0 = (u32*)ws;
    u32*  y1 = (u32*)(ws + xbytes);
    u32*  y2 = (u32*)(ws + 2 * xbytes);
    int2* pe = (int2*)(ws + 3 * xbytes);
    int*  row_ptr = (int*)(ws + 3 * xbytes + pebytes);

    int nvec = n * (EMB / 4);

    // x0 (bf16) = concat(user, item)
    init_x_kernel<<<(nvec + 255) / 256, 256, 0, stream>>>(
        (const float4*)user_emb, (const float4*)item_emb,
        (ushort4*)x0, n_users * (EMB / 4), nvec);

    // CSR row pointers from sorted rows
    build_row_ptr_kernel<<<(n + 1 + 255) / 256, 256, 0, stream>>>(
        adj_rows, nnz, n, row_ptr);

    // padded edge array {byte_off, val}, pad to multiple of 4
    expand_kernel<<<(nnz + 255) / 256, 256, 0, stream>>>(
        adj_rows, adj_cols, adj_vals, row_ptr, nnz, pe);

    // layers 1,2 -> bf16 y; layer 3 fused with mean epilogue -> fp32 out
    int blocks = (n * 8 + 255) / 256;   // 8 lanes per row, 32 rows per block
    spmm_kernel<<<blocks, 256, 0, stream>>>(row_ptr, pe, x0, (uint4*)y1, n);
    spmm_kernel<<<blocks, 256, 0, stream>>>(row_ptr, pe, y1, (uint4*)y2, n);
    spmm_final_kernel<<<blocks, 256, 0, stream>>>(
        row_ptr, pe, (const uint4*)x0, (const uint4*)y1, (const uint4*)y2,
        (float4*)d_out, n);
}

// Round 9
// 274.797 us; speedup vs baseline: 1.3505x; 1.3505x over previous
//
#include <hip/hip_runtime.h>
#include <hip/hip_bf16.h>

// LightGCN forward: x0 = concat(user_emb, item_emb); 3x { x = A*x }; out = (x0+x1+x2+x3)/4.
// Sorted COO -> CSR row_ptr (binary search). Edges pre-expanded into PADDED
// array pe[]: row r's segment starts at row_ptr[r] + 4*r (capacity deg+4),
// entry = {byte offset col*128, val fp32}, zero-padded to multiple of 4.
// SpMM: one 8-LANE GROUP per row; lane holds 8 dims (dwordx4 = whole 128B
// bf16 row per gather). Hot path: unconditionally load 16 pe entries +
// issue 16 masked gathers (one exposed latency chain); deg>16 (~3%) takes a
// 4-wide tail loop. __launch_bounds__(256,3) raises the VGPR cap to ~170 so
// the 16 in-flight uint4 gathers DON'T SPILL (R8's failure mode: cap=64 ->
// 93MB scratch writes). Layer 3 fused with mean epilogue.

#define EMB 64

typedef unsigned short u16;
typedef unsigned int   u32;
typedef unsigned long long u64;

__device__ __forceinline__ u16 f2bf(float f) {      // round-to-nearest-even
    u32 u = __float_as_uint(f);
    return (u16)((u + 0x7FFFu + ((u >> 16) & 1u)) >> 16);
}
__device__ __forceinline__ float bflo(u32 p) { return __uint_as_float(p << 16); }
__device__ __forceinline__ float bfhi(u32 p) { return __uint_as_float(p & 0xFFFF0000u); }
__device__ __forceinline__ u32 pack2(float hi, float lo) {
    return ((u32)f2bf(hi) << 16) | (u32)f2bf(lo);
}

__global__ void init_x_kernel(const float4* __restrict__ user,
                              const float4* __restrict__ item,
                              ushort4* __restrict__ x,
                              int n_user_vec, int n_total_vec) {
    int i = blockIdx.x * blockDim.x + threadIdx.x;
    if (i >= n_total_vec) return;
    float4 v = (i < n_user_vec) ? user[i] : item[i - n_user_vec];
    ushort4 o;
    o.x = f2bf(v.x); o.y = f2bf(v.y); o.z = f2bf(v.z); o.w = f2bf(v.w);
    x[i] = o;
}

// row_ptr[r] = lower_bound(rows, r); rows sorted.
__global__ void build_row_ptr_kernel(const int* __restrict__ rows, int nnz,
                                     int n_rows, int* __restrict__ row_ptr) {
    int r = blockIdx.x * blockDim.x + threadIdx.x;
    if (r > n_rows) return;
    int lo = 0, hi = nnz;
    while (lo < hi) {
        int mid = (lo + hi) >> 1;
        if (rows[mid] < r) lo = mid + 1; else hi = mid;
    }
    row_ptr[r] = lo;
}

// pe[e + 4*rows[e]] = {cols[e]*128, vals[e]}; last edge of each row zero-fills
// the <=3 pad slots up to the row's ceil4(deg) boundary.
__global__ void expand_kernel(const int* __restrict__ rows,
                              const int* __restrict__ cols,
                              const float* __restrict__ vals,
                              const int* __restrict__ row_ptr,
                              int nnz, int2* __restrict__ pe) {
    int e = blockIdx.x * blockDim.x + threadIdx.x;
    if (e >= nnz) return;
    int r = rows[e];
    int dst = e + 4 * r;
    int2 ent;
    ent.x = cols[e] << 7;                    // byte offset into bf16 x table
    ent.y = __float_as_int(vals[e]);
    pe[dst] = ent;
    bool last = (e == nnz - 1) || (rows[e + 1] != r);
    if (last) {
        int s   = row_ptr[r];
        int deg = e + 1 - s;
        int cnt = (deg + 3) & ~3;
        int lim = s + 4 * r + cnt;           // segment start + padded count
        int2 z; z.x = 0; z.y = 0;
        for (int j = dst + 1; j < lim; ++j) pe[j] = z;
    }
}

// Core row accumulate for one 8-lane group. lane sub holds dims 8sub..8sub+7.
// Unconditional 16-entry block (masked); rare tail for cnt > 16.
__device__ __forceinline__ void spmm_row16(const int2* __restrict__ pe,
                                           const char* __restrict__ xb,
                                           int ps, int cnt, u32 lane_byte,
                                           float* a /*[8]*/) {
#pragma unroll
    for (int k = 0; k < 8; ++k) a[k] = 0.0f;

    const u64* pq = (const u64*)(pe + ps);
    u32   offs[16];
    float vv[16];
#pragma unroll
    for (int k = 0; k < 16; ++k) {
        u64 q = __builtin_nontemporal_load(&pq[k]);   // uniform across group
        bool ok = k < cnt;
        offs[k] = ok ? (u32)q : 0u;                   // masked -> x[0] (L1-hot)
        vv[k]   = ok ? __uint_as_float((u32)(q >> 32)) : 0.0f;
    }
    uint4 xp[16];
#pragma unroll
    for (int k = 0; k < 16; ++k)
        xp[k] = *(const uint4*)(xb + (offs[k] + lane_byte));
#pragma unroll
    for (int k = 0; k < 16; ++k) {
        float v = vv[k];
        a[0] = fmaf(v, bflo(xp[k].x), a[0]);
        a[1] = fmaf(v, bfhi(xp[k].x), a[1]);
        a[2] = fmaf(v, bflo(xp[k].y), a[2]);
        a[3] = fmaf(v, bfhi(xp[k].y), a[3]);
        a[4] = fmaf(v, bflo(xp[k].z), a[4]);
        a[5] = fmaf(v, bfhi(xp[k].z), a[5]);
        a[6] = fmaf(v, bflo(xp[k].w), a[6]);
        a[7] = fmaf(v, bfhi(xp[k].w), a[7]);
    }

    // tail: deg > 16 (~3% of rows), 4-wide
    for (int j = 16; j < cnt; j += 4) {
        int2 ent[4];
#pragma unroll
        for (int k = 0; k < 4; ++k) ent[k] = pe[ps + j + k];
        uint4 tp[4];
#pragma unroll
        for (int k = 0; k < 4; ++k)
            tp[k] = *(const uint4*)(xb + ((u32)ent[k].x + lane_byte));
#pragma unroll
        for (int k = 0; k < 4; ++k) {
            float v = __int_as_float(ent[k].y);
            a[0] = fmaf(v, bflo(tp[k].x), a[0]);
            a[1] = fmaf(v, bfhi(tp[k].x), a[1]);
            a[2] = fmaf(v, bflo(tp[k].y), a[2]);
            a[3] = fmaf(v, bfhi(tp[k].y), a[3]);
            a[4] = fmaf(v, bflo(tp[k].z), a[4]);
            a[5] = fmaf(v, bfhi(tp[k].z), a[5]);
            a[6] = fmaf(v, bflo(tp[k].w), a[6]);
            a[7] = fmaf(v, bfhi(tp[k].w), a[7]);
        }
    }
}

__global__ __launch_bounds__(256, 3)
void spmm_kernel(const int* __restrict__ row_ptr,
                 const int2* __restrict__ pe,
                 const u32* __restrict__ x,    // bf16x2 table [n*32]
                 uint4* __restrict__ y,        // bf16 rows as uint4 [n*8]
                 int n_rows) {
    int tid = blockIdx.x * blockDim.x + threadIdx.x;
    int row = tid >> 3;
    int sub = threadIdx.x & 7;
    if (row >= n_rows) return;

    int s   = row_ptr[row];
    int deg = row_ptr[row + 1] - s;
    int cnt = (deg + 3) & ~3;
    int ps  = s + 4 * row;

    float a[8];
    spmm_row16(pe, (const char*)x, ps, cnt, (u32)sub * 16u, a);

    uint4 w;
    w.x = pack2(a[1], a[0]);
    w.y = pack2(a[3], a[2]);
    w.z = pack2(a[5], a[4]);
    w.w = pack2(a[7], a[6]);
    y[(size_t)row * 8 + sub] = w;
}

// Layer 3 fused with epilogue: out = (x0 + y1 + y2 + A*y2) * 0.25 (fp32 out).
__global__ __launch_bounds__(256, 3)
void spmm_final_kernel(const int* __restrict__ row_ptr,
                       const int2* __restrict__ pe,
                       const uint4* __restrict__ x0,   // bf16 rows [n*8]
                       const uint4* __restrict__ y1,
                       const uint4* __restrict__ y2,   // also gather src
                       float4* __restrict__ out,       // [n*16]
                       int n_rows) {
    int tid = blockIdx.x * blockDim.x + threadIdx.x;
    int row = tid >> 3;
    int sub = threadIdx.x & 7;
    if (row >= n_rows) return;

    int s   = row_ptr[row];
    int deg = row_ptr[row + 1] - s;
    int cnt = (deg + 3) & ~3;
    int ps  = s + 4 * row;

    float a[8];
    spmm_row16(pe, (const char*)y2, ps, cnt, (u32)sub * 16u, a);

    size_t i8 = (size_t)row * 8 + sub;
    uint4 b0 = x0[i8], b1 = y1[i8], b2 = y2[i8];
    float4 r0, r1;
    r0.x = (bflo(b0.x) + bflo(b1.x) + bflo(b2.x) + a[0]) * 0.25f;
    r0.y = (bfhi(b0.x) + bfhi(b1.x) + bfhi(b2.x) + a[1]) * 0.25f;
    r0.z = (bflo(b0.y) + bflo(b1.y) + bflo(b2.y) + a[2]) * 0.25f;
    r0.w = (bfhi(b0.y) + bfhi(b1.y) + bfhi(b2.y) + a[3]) * 0.25f;
    r1.x = (bflo(b0.z) + bflo(b1.z) + bflo(b2.z) + a[4]) * 0.25f;
    r1.y = (bfhi(b0.z) + bfhi(b1.z) + bfhi(b2.z) + a[5]) * 0.25f;
    r1.z = (bflo(b0.w) + bflo(b1.w) + bflo(b2.w) + a[6]) * 0.25f;
    r1.w = (bfhi(b0.w) + bfhi(b1.w) + bfhi(b2.w) + a[7]) * 0.25f;
    size_t o4 = (size_t)row * 16 + (size_t)sub * 2;
    out[o4]     = r0;
    out[o4 + 1] = r1;
}

extern "C" void kernel_launch(void* const* d_in, const int* in_sizes, int n_in,
                              void* d_out, int out_size, void* d_ws, size_t ws_size,
                              hipStream_t stream) {
    const float* user_emb = (const float*)d_in[0];
    const float* item_emb = (const float*)d_in[1];
    const int*   adj_rows = (const int*)d_in[2];
    const int*   adj_cols = (const int*)d_in[3];
    const float* adj_vals = (const float*)d_in[4];

    const int n_users = in_sizes[0] / EMB;
    const int n_items = in_sizes[1] / EMB;
    const int nnz     = in_sizes[2];
    const int n       = n_users + n_items;

    char* ws = (char*)d_ws;
    size_t xbytes  = (size_t)n * EMB * sizeof(u16);                // 38.4 MB
    // +16 entries slack: spmm_row16 reads up to 15 entries past the last
    // segment (masked, never dereferenced as gather addresses).
    size_t pebytes = ((size_t)nnz + 4 * (size_t)n + 16) * sizeof(int2);
    u32*  x0 = (u32*)ws;
    u32*  y1 = (u32*)(ws + xbytes);
    u32*  y2 = (u32*)(ws + 2 * xbytes);
    int2* pe = (int2*)(ws + 3 * xbytes);
    int*  row_ptr = (int*)(ws + 3 * xbytes + pebytes);

    int nvec = n * (EMB / 4);

    // x0 (bf16) = concat(user, item)
    init_x_kernel<<<(nvec + 255) / 256, 256, 0, stream>>>(
        (const float4*)user_emb, (const float4*)item_emb,
        (ushort4*)x0, n_users * (EMB / 4), nvec);

    // CSR row pointers from sorted rows
    build_row_ptr_kernel<<<(n + 1 + 255) / 256, 256, 0, stream>>>(
        adj_rows, nnz, n, row_ptr);

    // padded edge array {byte_off, val}, pad to multiple of 4
    expand_kernel<<<(nnz + 255) / 256, 256, 0, stream>>>(
        adj_rows, adj_cols, adj_vals, row_ptr, nnz, pe);

    // layers 1,2 -> bf16 y; layer 3 fused with mean epilogue -> fp32 out
    int blocks = (n * 8 + 255) / 256;   // 8 lanes per row, 32 rows per block
    spmm_kernel<<<blocks, 256, 0, stream>>>(row_ptr, pe, x0, (uint4*)y1, n);
    spmm_kernel<<<blocks, 256, 0, stream>>>(row_ptr, pe, y1, (uint4*)y2, n);
    spmm_final_kernel<<<blocks, 256, 0, stream>>>(
        row_ptr, pe, (const uint4*)x0, (const uint4*)y1, (const uint4*)y2,
        (float4*)d_out, n);
}

// Round 10
// 273.883 us; speedup vs baseline: 1.3550x; 1.0033x over previous
//
#include <hip/hip_runtime.h>
#include <hip/hip_bf16.h>

// LightGCN forward: x0 = concat(user_emb, item_emb); 3x { x = A*x }; out = (x0+x1+x2+x3)/4.
// Sorted COO -> CSR row_ptr (binary search). Edges pre-expanded into PADDED
// array pe[]: row r's segment starts at row_ptr[r] + 4*r (capacity deg+4),
// entry = {byte offset col*128, val fp32}, zero-padded to multiple of 4.
// SpMM: one 8-LANE GROUP per row; lane holds 8 dims (dwordx4 = whole 128B
// bf16 row per gather). 8-wide masked gather batches: 8 independent uint4
// gathers in flight per row iteration (~32 VGPR), fits under the 64-VGPR
// occupancy class with NO __launch_bounds__ (R8: 16-wide @cap64 spilled;
// R9: 16-wide @cap170 ran at 26% occupancy, same dur as R7).
// Layer 3 fused with mean epilogue.

#define EMB 64

typedef unsigned short u16;
typedef unsigned int   u32;
typedef unsigned long long u64;

__device__ __forceinline__ u16 f2bf(float f) {      // round-to-nearest-even
    u32 u = __float_as_uint(f);
    return (u16)((u + 0x7FFFu + ((u >> 16) & 1u)) >> 16);
}
__device__ __forceinline__ float bflo(u32 p) { return __uint_as_float(p << 16); }
__device__ __forceinline__ float bfhi(u32 p) { return __uint_as_float(p & 0xFFFF0000u); }
__device__ __forceinline__ u32 pack2(float hi, float lo) {
    return ((u32)f2bf(hi) << 16) | (u32)f2bf(lo);
}

__global__ void init_x_kernel(const float4* __restrict__ user,
                              const float4* __restrict__ item,
                              ushort4* __restrict__ x,
                              int n_user_vec, int n_total_vec) {
    int i = blockIdx.x * blockDim.x + threadIdx.x;
    if (i >= n_total_vec) return;
    float4 v = (i < n_user_vec) ? user[i] : item[i - n_user_vec];
    ushort4 o;
    o.x = f2bf(v.x); o.y = f2bf(v.y); o.z = f2bf(v.z); o.w = f2bf(v.w);
    x[i] = o;
}

// row_ptr[r] = lower_bound(rows, r); rows sorted.
__global__ void build_row_ptr_kernel(const int* __restrict__ rows, int nnz,
                                     int n_rows, int* __restrict__ row_ptr) {
    int r = blockIdx.x * blockDim.x + threadIdx.x;
    if (r > n_rows) return;
    int lo = 0, hi = nnz;
    while (lo < hi) {
        int mid = (lo + hi) >> 1;
        if (rows[mid] < r) lo = mid + 1; else hi = mid;
    }
    row_ptr[r] = lo;
}

// pe[e + 4*rows[e]] = {cols[e]*128, vals[e]}; last edge of each row zero-fills
// the <=3 pad slots up to the row's ceil4(deg) boundary.
__global__ void expand_kernel(const int* __restrict__ rows,
                              const int* __restrict__ cols,
                              const float* __restrict__ vals,
                              const int* __restrict__ row_ptr,
                              int nnz, int2* __restrict__ pe) {
    int e = blockIdx.x * blockDim.x + threadIdx.x;
    if (e >= nnz) return;
    int r = rows[e];
    int dst = e + 4 * r;
    int2 ent;
    ent.x = cols[e] << 7;                    // byte offset into bf16 x table
    ent.y = __float_as_int(vals[e]);
    pe[dst] = ent;
    bool last = (e == nnz - 1) || (rows[e + 1] != r);
    if (last) {
        int s   = row_ptr[r];
        int deg = e + 1 - s;
        int cnt = (deg + 3) & ~3;
        int lim = s + 4 * r + cnt;           // segment start + padded count
        int2 z; z.x = 0; z.y = 0;
        for (int j = dst + 1; j < lim; ++j) pe[j] = z;
    }
}

// Core row accumulate for one 8-lane group. lane sub holds dims 8sub..8sub+7.
// 8-wide masked batches: 8 independent gathers in flight per iteration.
// Masked slots (beyond cnt) read pe garbage within the +16-slack allocation
// (safe) and are cndmask'd to {off=0, val=0} -> gather hits the L1-hot x[0]
// line, multiplied by 0.
__device__ __forceinline__ void spmm_row8w(const int2* __restrict__ pe,
                                           const char* __restrict__ xb,
                                           int ps, int cnt, u32 lane_byte,
                                           float* a /*[8]*/) {
#pragma unroll
    for (int k = 0; k < 8; ++k) a[k] = 0.0f;

    const u64* pq = (const u64*)(pe + ps);
    for (int j = 0; j < cnt; j += 8) {
        u32   offs[8];
        float vv[8];
#pragma unroll
        for (int k = 0; k < 8; ++k) {
            u64 q = __builtin_nontemporal_load(&pq[j + k]);  // uniform across group
            bool ok = (j + k) < cnt;
            offs[k] = ok ? (u32)q : 0u;
            vv[k]   = ok ? __uint_as_float((u32)(q >> 32)) : 0.0f;
        }
        uint4 xp[8];
#pragma unroll
        for (int k = 0; k < 8; ++k)
            xp[k] = *(const uint4*)(xb + (offs[k] + lane_byte));
#pragma unroll
        for (int k = 0; k < 8; ++k) {
            float v = vv[k];
            a[0] = fmaf(v, bflo(xp[k].x), a[0]);
            a[1] = fmaf(v, bfhi(xp[k].x), a[1]);
            a[2] = fmaf(v, bflo(xp[k].y), a[2]);
            a[3] = fmaf(v, bfhi(xp[k].y), a[3]);
            a[4] = fmaf(v, bflo(xp[k].z), a[4]);
            a[5] = fmaf(v, bfhi(xp[k].z), a[5]);
            a[6] = fmaf(v, bflo(xp[k].w), a[6]);
            a[7] = fmaf(v, bfhi(xp[k].w), a[7]);
        }
    }
}

__global__ void spmm_kernel(const int* __restrict__ row_ptr,
                            const int2* __restrict__ pe,
                            const u32* __restrict__ x,    // bf16x2 table [n*32]
                            uint4* __restrict__ y,        // bf16 rows as uint4 [n*8]
                            int n_rows) {
    int tid = blockIdx.x * blockDim.x + threadIdx.x;
    int row = tid >> 3;
    int sub = threadIdx.x & 7;
    if (row >= n_rows) return;

    int s   = row_ptr[row];
    int deg = row_ptr[row + 1] - s;
    int cnt = (deg + 3) & ~3;
    int ps  = s + 4 * row;

    float a[8];
    spmm_row8w(pe, (const char*)x, ps, cnt, (u32)sub * 16u, a);

    uint4 w;
    w.x = pack2(a[1], a[0]);
    w.y = pack2(a[3], a[2]);
    w.z = pack2(a[5], a[4]);
    w.w = pack2(a[7], a[6]);
    y[(size_t)row * 8 + sub] = w;
}

// Layer 3 fused with epilogue: out = (x0 + y1 + y2 + A*y2) * 0.25 (fp32 out).
__global__ void spmm_final_kernel(const int* __restrict__ row_ptr,
                                  const int2* __restrict__ pe,
                                  const uint4* __restrict__ x0,   // bf16 rows [n*8]
                                  const uint4* __restrict__ y1,
                                  const uint4* __restrict__ y2,   // also gather src
                                  float4* __restrict__ out,       // [n*16]
                                  int n_rows) {
    int tid = blockIdx.x * blockDim.x + threadIdx.x;
    int row = tid >> 3;
    int sub = threadIdx.x & 7;
    if (row >= n_rows) return;

    int s   = row_ptr[row];
    int deg = row_ptr[row + 1] - s;
    int cnt = (deg + 3) & ~3;
    int ps  = s + 4 * row;

    float a[8];
    spmm_row8w(pe, (const char*)y2, ps, cnt, (u32)sub * 16u, a);

    size_t i8 = (size_t)row * 8 + sub;
    uint4 b0 = x0[i8], b1 = y1[i8], b2 = y2[i8];
    float4 r0, r1;
    r0.x = (bflo(b0.x) + bflo(b1.x) + bflo(b2.x) + a[0]) * 0.25f;
    r0.y = (bfhi(b0.x) + bfhi(b1.x) + bfhi(b2.x) + a[1]) * 0.25f;
    r0.z = (bflo(b0.y) + bflo(b1.y) + bflo(b2.y) + a[2]) * 0.25f;
    r0.w = (bfhi(b0.y) + bfhi(b1.y) + bfhi(b2.y) + a[3]) * 0.25f;
    r1.x = (bflo(b0.z) + bflo(b1.z) + bflo(b2.z) + a[4]) * 0.25f;
    r1.y = (bfhi(b0.z) + bfhi(b1.z) + bfhi(b2.z) + a[5]) * 0.25f;
    r1.z = (bflo(b0.w) + bflo(b1.w) + bflo(b2.w) + a[6]) * 0.25f;
    r1.w = (bfhi(b0.w) + bfhi(b1.w) + bfhi(b2.w) + a[7]) * 0.25f;
    size_t o4 = (size_t)row * 16 + (size_t)sub * 2;
    out[o4]     = r0;
    out[o4 + 1] = r1;
}

extern "C" void kernel_launch(void* const* d_in, const int* in_sizes, int n_in,
                              void* d_out, int out_size, void* d_ws, size_t ws_size,
                              hipStream_t stream) {
    const float* user_emb = (const float*)d_in[0];
    const float* item_emb = (const float*)d_in[1];
    const int*   adj_rows = (const int*)d_in[2];
    const int*   adj_cols = (const int*)d_in[3];
    const float* adj_vals = (const float*)d_in[4];

    const int n_users = in_sizes[0] / EMB;
    const int n_items = in_sizes[1] / EMB;
    const int nnz     = in_sizes[2];
    const int n       = n_users + n_items;

    char* ws = (char*)d_ws;
    size_t xbytes  = (size_t)n * EMB * sizeof(u16);                // 38.4 MB
    // +16 entries slack: spmm_row8w reads up to 7 entries past the last
    // segment (masked, never used as gather addresses).
    size_t pebytes = ((size_t)nnz + 4 * (size_t)n + 16) * sizeof(int2);
    u32*  x0 = (u32*)ws;
    u32*  y1 = (u32*)(ws + xbytes);
    u32*  y2 = (u32*)(ws + 2 * xbytes);
    int2* pe = (int2*)(ws + 3 * xbytes);
    int*  row_ptr = (int*)(ws + 3 * xbytes + pebytes);

    int nvec = n * (EMB / 4);

    // x0 (bf16) = concat(user, item)
    init_x_kernel<<<(nvec + 255) / 256, 256, 0, stream>>>(
        (const float4*)user_emb, (const float4*)item_emb,
        (ushort4*)x0, n_users * (EMB / 4), nvec);

    // CSR row pointers from sorted rows
    build_row_ptr_kernel<<<(n + 1 + 255) / 256, 256, 0, stream>>>(
        adj_rows, nnz, n, row_ptr);

    // padded edge array {byte_off, val}, pad to multiple of 4
    expand_kernel<<<(nnz + 255) / 256, 256, 0, stream>>>(
        adj_rows, adj_cols, adj_vals, row_ptr, nnz, pe);

    // layers 1,2 -> bf16 y; layer 3 fused with mean epilogue -> fp32 out
    int blocks = (n * 8 + 255) / 256;   // 8 lanes per row, 32 rows per block
    spmm_kernel<<<blocks, 256, 0, stream>>>(row_ptr, pe, x0, (uint4*)y1, n);
    spmm_kernel<<<blocks, 256, 0, stream>>>(row_ptr, pe, y1, (uint4*)y2, n);
    spmm_final_kernel<<<blocks, 256, 0, stream>>>(
        row_ptr, pe, (const uint4*)x0, (const uint4*)y1, (const uint4*)y2,
        (float4*)d_out, n);
}